// Round 1
// 1800.194 us; speedup vs baseline: 1.0752x; 1.0752x over previous
//
#include <hip/hip_runtime.h>
#include <hip/hip_bf16.h>

// Problem dims (fixed)
#define NB 1024   // batch
#define NI 256    // input size
#define NH 256    // hidden
#define NT 64     // window T
#define TM1 63    // T-1 steps

typedef short bf16x8 __attribute__((ext_vector_type(8)));
typedef float f32x4 __attribute__((ext_vector_type(4)));

__device__ __forceinline__ float bf2f(__hip_bfloat16 x){ return __bfloat162float(x); }
__device__ __forceinline__ float bf16s_to_f(short s){
    unsigned u = ((unsigned)(unsigned short)s) << 16;
    return __builtin_bit_cast(float, u);
}
__device__ __forceinline__ unsigned short f_to_bf16s(float f){
    __hip_bfloat16 h = __float2bfloat16(f);
    return *(unsigned short*)&h;
}
__device__ __forceinline__ unsigned pack_bf16(float lo, float hi){
    return (unsigned)f_to_bf16s(lo) | ((unsigned)f_to_bf16s(hi) << 16);
}

__device__ __forceinline__ float fast_exp2(float x){ return __builtin_amdgcn_exp2f(x); }
__device__ __forceinline__ float fast_rcp(float x){ return __builtin_amdgcn_rcpf(x); }
__device__ __forceinline__ float fast_tanh(float x){
    float e = fast_exp2(x * 2.8853900817779268f);   // 2*log2(e)
    return 1.f - 2.f * fast_rcp(e + 1.f);
}
__device__ __forceinline__ float fast_sigmoid(float x){
    return fast_rcp(1.f + fast_exp2(-1.4426950408889634f * x));
}

// ---------------------------------------------------------------------------
// One-time prep.
// blocks 0..1023:  W2[n][k] = bf16(k<256 ? Wih[n][k] : Whh[n][k-256]); bias=bih+bhh
// blocks 1024..1151: Wh3[jt][u][k] bf16, k<16 -> Wh[jt*16+k][u], k>=16 -> Wh[256+jt*16+k-16][u]
// ---------------------------------------------------------------------------
__global__ __launch_bounds__(256) void prep_w2(
    const float* __restrict__ Wih, const float* __restrict__ Whh,
    const float* __restrict__ bih, const float* __restrict__ bhh,
    const float* __restrict__ Wh,
    __hip_bfloat16* __restrict__ W2, float* __restrict__ bias,
    __hip_bfloat16* __restrict__ Wh3)
{
    int tid = threadIdx.x;
    if (blockIdx.x < 1024){
        int n = blockIdx.x;
        W2[(long)n*512 + tid]       = __float2bfloat16(Wih[(long)n*256 + tid]);
        W2[(long)n*512 + 256 + tid] = __float2bfloat16(Whh[(long)n*256 + tid]);
        if (tid == 0) bias[n] = bih[n] + bhh[n];
    } else {
        int idx = (blockIdx.x - 1024) * 256 + tid;   // 0..32767
        int k  = idx & 31;
        int u  = (idx >> 5) & 63;
        int jt = idx >> 11;
        float v = (k < 16) ? Wh[(jt*16 + k)*NT + u]
                           : Wh[(256 + jt*16 + (k - 16))*NT + u];
        Wh3[idx] = __float2bfloat16(v);   // layout ((jt*64)+u)*32+k == idx
    }
}

// ---------------------------------------------------------------------------
// prefsT[b][i][u] = b_fs[u] + sum_t FS[b][t][i]*W_fs[t][u]   (bf16, u-contig)
// Restructured: accumulate the full 64-wide u-row in registers (16 x f32x4
// independent chains), single pass over t. One coalesced global dword +
// 16 broadcast ds_read_b128 per t. Latency-bound -> issue-bound.
// ---------------------------------------------------------------------------
__global__ __launch_bounds__(256) void prefs_kernel(
    const float* __restrict__ FS,    // [B][63][I] f32
    const float* __restrict__ Wfs,   // [64][64]   f32
    const float* __restrict__ bfs,   // [64]       f32
    __hip_bfloat16* __restrict__ prefsT)  // [B][I][64] bf16
{
    __shared__ float wfs_s[TM1][NT];     // 15.75 KB
    int b = blockIdx.x, tid = threadIdx.x;
    for (int idx = tid; idx < TM1*NT; idx += 256)
        wfs_s[idx >> 6][idx & 63] = Wfs[idx];
    __syncthreads();

    const float* fsp = FS + (long)b*TM1*NI + tid;   // this thread's i column

    f32x4 acc[16];
    #pragma unroll
    for (int g = 0; g < 16; ++g) acc[g] = *(const f32x4*)(bfs + g*4);

    #pragma unroll 4
    for (int t = 0; t < TM1; ++t){
        float fs = fsp[(long)t*NI];
        #pragma unroll
        for (int g = 0; g < 16; ++g){
            f32x4 w4 = *(const f32x4*)&wfs_s[t][g*4];
            acc[g] += fs * w4;
        }
    }

    uint4* dst = (uint4*)(prefsT + ((long)b*NI + tid)*NT);
    #pragma unroll
    for (int g = 0; g < 16; g += 2){
        uint4 v;
        v.x = pack_bf16(acc[g][0],   acc[g][1]);
        v.y = pack_bf16(acc[g][2],   acc[g][3]);
        v.z = pack_bf16(acc[g+1][0], acc[g+1][1]);
        v.w = pack_bf16(acc[g+1][2], acc[g+1][3]);
        dst[g >> 1] = v;
    }
}

// ---------------------------------------------------------------------------
// Per step t, one block per batch b:
//   s2[u] = sum_jt s2part[jt][b][u] + bh[u] + y_t*Wfs[63][u]
//   attn[i] = b_attn + sum_u tanh(s2[u] + prefsT[b][i][u]) * Wattn[u]
//   a = softmax_i(attn);  w = a*FS[b][t][i] -> out_iw f32, Xcur[b][0:256] bf16
// s2part reduction parallelized across all 4 waves (4 loads each) + LDS combine.
// ---------------------------------------------------------------------------
__global__ __launch_bounds__(256) void attn_kernel(
    int t,
    const float* __restrict__ FS,      // [B][63][I]
    const float* __restrict__ yhist,   // [B][63]
    const float* __restrict__ bh,      // [64]
    const float* __restrict__ Wfs,     // [64][64] (last row)
    const float* __restrict__ Wattn,   // [64]
    const float* __restrict__ battn,   // [1]
    const __hip_bfloat16* __restrict__ prefsT, // [B][I][64]
    const float* __restrict__ s2part,  // [16][B][64]
    __hip_bfloat16* __restrict__ Xcur, // [B][512]
    float* __restrict__ out_iw)        // [B][63][I] f32
{
    __shared__ float s2_s[NT];
    __shared__ float wattn_s[NT];
    __shared__ float s2red[4][NT];
    __shared__ float red[4];
    int b = blockIdx.x, tid = threadIdx.x;
    int wid = tid >> 6;

    // preload prefs for this thread's i (8 x dwordx4) -- issue first, overlaps s2 work
    const bf16x8* pfT = (const bf16x8*)(prefsT + ((long)b*NI + tid)*NT);
    bf16x8 pf[8];
    #pragma unroll
    for (int o = 0; o < 8; ++o) pf[o] = pfT[o];

    // distributed partial sum: wave w loads jt in {w, w+4, w+8, w+12}
    {
        int u = tid & 63, grp = wid;
        float acc4 = 0.f;
        #pragma unroll
        for (int q = 0; q < 4; ++q)
            acc4 += s2part[((long)(grp + 4*q)*NB + b)*NT + u];
        s2red[grp][u] = acc4;
    }
    __syncthreads();
    if (tid < NT){
        float y = yhist[b*TM1 + t];
        s2_s[tid] = s2red[0][tid] + s2red[1][tid] + s2red[2][tid] + s2red[3][tid]
                  + bh[tid] + y * Wfs[TM1*NT + tid];
        wattn_s[tid] = Wattn[tid];
    }
    __syncthreads();

    float acc = 0.f;
    #pragma unroll
    for (int o = 0; o < 8; ++o){
        #pragma unroll
        for (int j = 0; j < 8; ++j){
            float x = s2_s[o*8 + j] + bf16s_to_f(pf[o][j]);
            acc = fmaf(fast_tanh(x), wattn_s[o*8 + j], acc);
        }
    }
    float attn = acc + battn[0];

    // softmax over 256 lanes
    float m = attn;
    #pragma unroll
    for (int o = 32; o > 0; o >>= 1) m = fmaxf(m, __shfl_xor(m, o, 64));
    if ((tid & 63) == 0) red[wid] = m;
    __syncthreads();
    m = fmaxf(fmaxf(red[0], red[1]), fmaxf(red[2], red[3]));
    __syncthreads();
    float p = fast_exp2((attn - m) * 1.4426950408889634f);
    float ssum = p;
    #pragma unroll
    for (int o = 32; o > 0; o >>= 1) ssum += __shfl_xor(ssum, o, 64);
    if ((tid & 63) == 0) red[wid] = ssum;
    __syncthreads();
    ssum = red[0] + red[1] + red[2] + red[3];
    float a = p * fast_rcp(ssum);

    float w = a * FS[((long)b*TM1 + t)*NI + tid];
    Xcur[b*512 + tid] = __float2bfloat16(w);
    out_iw[((long)b*TM1 + t)*NI + tid] = w;
}

// ---------------------------------------------------------------------------
// Per step t: gates = Xcur @ W2^T (+bias), LSTM pointwise.
//  writes: c (f32), out_ie (f32), Xnext h-half (bf16),
//  and s2part[by][b][u] = partial hc@Wh for its j-tile (mini-MFMA via LDS).
// grid (16 mtiles, 16 jtiles) x 256 thr (4 waves; wave = 16 batches).
// MFMA 16x16x32 bf16; A: m=lane&15,k=(lane>>4)*8+j ; B: n=lane&15, same k ;
// C/D: col=lane&15, row=(lane>>4)*4+reg   [learn_hip m89-verified]
// ---------------------------------------------------------------------------
__global__ __launch_bounds__(256) void gates_kernel(
    int t,
    const __hip_bfloat16* __restrict__ W2,    // [1024][512] bf16
    const float* __restrict__ bias,           // [1024] f32
    const __hip_bfloat16* __restrict__ Wh3,   // [16][64][32] bf16
    const __hip_bfloat16* __restrict__ Xcur,  // [B][512]
    float* __restrict__ c,                    // [B][256] f32 state
    __hip_bfloat16* __restrict__ Xnext,       // [B][512] (h half)
    float* __restrict__ s2part,               // [16][B][64] f32
    float* __restrict__ out_ie)               // [B][63][NH] f32
{
    __shared__ __hip_bfloat16 hc_lds[64][32];   // [mloc][k]: k<16 h, k>=16 c

    int tid  = threadIdx.x;
    int wave = tid >> 6, lane = tid & 63;
    int bx = blockIdx.x, by = blockIdx.y;
    int m0 = bx * 64 + wave * 16;
    int j0 = by * 16;
    int lm = lane & 15;
    int lk = (lane >> 4) * 8;

    f32x4 acc[4] = {};
    const __hip_bfloat16* xrow = Xcur + (long)(m0 + lm) * 512;

    for (int kc = 0; kc < 16; ++kc){
        int kb = kc * 32 + lk;
        bf16x8 afrag = *(const bf16x8*)(xrow + kb);
        #pragma unroll
        for (int q = 0; q < 4; ++q){
            int ncol = q * 256 + j0 + lm;
            bf16x8 bfrag = *(const bf16x8*)(W2 + (long)ncol * 512 + kb);
            acc[q] = __builtin_amdgcn_mfma_f32_16x16x32_bf16(afrag, bfrag, acc[q], 0, 0, 0);
        }
    }

    int j = j0 + lm;
    float bb[4];
    #pragma unroll
    for (int q = 0; q < 4; ++q) bb[q] = bias[q*256 + j];

    #pragma unroll
    for (int r = 0; r < 4; ++r){
        int mloc = wave*16 + (lane >> 4)*4 + r;
        int m = bx*64 + mloc;
        float ig = acc[0][r] + bb[0];
        float fg = acc[1][r] + bb[1];
        float gg = acc[2][r] + bb[2];
        float og = acc[3][r] + bb[3];
        float cold = c[m*NH + j];
        float cn = fast_sigmoid(fg) * cold + fast_sigmoid(ig) * fast_tanh(gg);
        float hn = fast_sigmoid(og) * fast_tanh(cn);
        c[m*NH + j] = cn;
        Xnext[(long)m*512 + 256 + j] = __float2bfloat16(hn);
        out_ie[((long)m*TM1 + t)*NH + j] = hn;
        hc_lds[mloc][lm]      = __float2bfloat16(hn);
        hc_lds[mloc][16 + lm] = __float2bfloat16(cn);
    }
    __syncthreads();

    // mini-GEMM: s2 partial for this j-tile: [64 m] x [64 u], K=32 (h|c of tile)
    bf16x8 af = *(const bf16x8*)&hc_lds[wave*16 + lm][lk];
    f32x4 sacc[4] = {};
    #pragma unroll
    for (int nt = 0; nt < 4; ++nt){
        bf16x8 bfrag = *(const bf16x8*)(Wh3 + ((long)by*64 + nt*16 + lm)*32 + lk);
        sacc[nt] = __builtin_amdgcn_mfma_f32_16x16x32_bf16(af, bfrag, sacc[nt], 0, 0, 0);
    }
    #pragma unroll
    for (int nt = 0; nt < 4; ++nt){
        int u = nt*16 + lm;
        #pragma unroll
        for (int r = 0; r < 4; ++r){
            int m = bx*64 + wave*16 + (lane >> 4)*4 + r;
            s2part[((long)by*NB + m)*NT + u] = sacc[nt][r];
        }
    }
}

// ---------------------------------------------------------------------------
extern "C" void kernel_launch(void* const* d_in, const int* in_sizes, int n_in,
                              void* d_out, int out_size, void* d_ws, size_t ws_size,
                              hipStream_t stream)
{
    const float* FS    = (const float*)d_in[0];
    const float* yh    = (const float*)d_in[1];
    const float* Wh    = (const float*)d_in[2];
    const float* bh    = (const float*)d_in[3];
    const float* Wfs   = (const float*)d_in[4];
    const float* bfs   = (const float*)d_in[5];
    const float* Wattn = (const float*)d_in[6];
    const float* battn = (const float*)d_in[7];
    const float* Wih   = (const float*)d_in[8];
    const float* Whh   = (const float*)d_in[9];
    const float* bih   = (const float*)d_in[10];
    const float* bhh   = (const float*)d_in[11];

    char* ws = (char*)d_ws;
    const size_t MB = 1048576;
    // layout: prefsT 32MB | X0 1MB | c 1MB | s2part 4MB | X1 1MB | W2 1MB | bias 4KB | Wh3 64KB
    __hip_bfloat16* prefsT = (__hip_bfloat16*)ws;
    size_t off = (size_t)NB * NI * NT * sizeof(__hip_bfloat16);   // 32 MB
    __hip_bfloat16* X0  = (__hip_bfloat16*)(ws + off);
    float* c            = (float*)(ws + off + 1*MB);
    float* s2part       = (float*)(ws + off + 2*MB);
    __hip_bfloat16* X1  = (__hip_bfloat16*)(ws + off + 6*MB);
    __hip_bfloat16* W2  = (__hip_bfloat16*)(ws + off + 7*MB);
    float* bias         = (float*)(ws + off + 8*MB);
    __hip_bfloat16* Wh3 = (__hip_bfloat16*)(ws + off + 8*MB + 4096);
    __hip_bfloat16* Xb[2] = {X0, X1};

    float* out_iw = (float*)d_out;                     // [B][63][I] f32
    float* out_ie = out_iw + (size_t)NB * TM1 * NI;    // [B][63][H] f32

    // zero X0 (h-half at t=0) + c + s2part (t=0 reads zeros): contiguous 6MB
    hipMemsetAsync(ws + off, 0, 6*MB, stream);

    prep_w2<<<1152, 256, 0, stream>>>(Wih, Whh, bih, bhh, Wh, W2, bias, Wh3);
    prefs_kernel<<<NB, 256, 0, stream>>>(FS, Wfs, bfs, prefsT);

    for (int t = 0; t < TM1; ++t){
        __hip_bfloat16* Xcur  = Xb[t & 1];
        __hip_bfloat16* Xnext = Xb[(t + 1) & 1];
        attn_kernel<<<NB, 256, 0, stream>>>(t, FS, yh, bh, Wfs, Wattn, battn,
                                            prefsT, s2part, Xcur, out_iw);
        gates_kernel<<<dim3(16,16), 256, 0, stream>>>(t, W2, bias, Wh3,
                                                      Xcur, c, Xnext, s2part, out_ie);
    }
}